// Round 4
// baseline (99.508 us; speedup 1.0000x reference)
//
#include <hip/hip_runtime.h>
#include <hip/hip_bf16.h>

// RBF fused single kernel: out[b][o] = exp(-max(||x||^2 - 2 x.c + ||c||^2, 0) * exp(-2 ls))
// B=8192, IN=512, OUT=1024 fp32. One kernel: reg-stage fp32 -> bf16 LDS (swizzled),
// in-flight row/col sum-of-squares (no separate convert pass, no bf16 HBM round-trip),
// 128x128 tile, 4 waves x 64x64, BK=32 dbuf, 1 barrier/K-step, MFMA 16x16x32 bf16.

#define B_ROWS 8192
#define IN_K   512
#define OUT_N  1024
#define BK     32
#define NKT    (IN_K / BK)   // 16

typedef __attribute__((ext_vector_type(8))) __bf16 bf16x8;
typedef __attribute__((ext_vector_type(4))) __bf16 bf16x4;
typedef __attribute__((ext_vector_type(4))) float  floatx4;

__global__ __launch_bounds__(256, 3) void rbf_fused(
    const float* __restrict__ X,    // [8192][512]
    const float* __restrict__ C,    // [1024][512]
    const float* __restrict__ LS,   // [1024]
    float* __restrict__ out)        // [8192][1024]
{
    // LDS: 2 x (128x32) bf16 per operand = 8KB/buf, 32KB total + sumsq arrays.
    __shared__ __bf16 As[2][128 * BK];
    __shared__ __bf16 Bs[2][128 * BK];
    __shared__ float  xsq_s[128];
    __shared__ float  csq_s[128];

    const int tid  = threadIdx.x;
    // XCD-aware swizzle (512 % 8 == 0, bijective): XCD x -> bm in [8x, 8x+8) x all bn,
    // keeping ~2MB X-panel + 2MB C (fp32) inside each XCD's 4MB L2.
    const int sid  = blockIdx.x;
    const int bidx = (sid & 7) * 64 + (sid >> 3);
    const int bm   = bidx >> 3;          // 0..63
    const int bn   = bidx & 7;           // 0..7
    const int brow = bm * 128;
    const int bcol = bn * 128;
    const int lane = tid & 63;
    const int w    = tid >> 6;
    const int wr   = w >> 1;             // 2x2 waves, each 64x64 output
    const int wc   = w & 1;
    const int l15  = lane & 15;
    const int l4   = lane >> 4;

    // Staging: tile 128 rows x 32 k fp32 = 1024 float4 per operand; thread t handles
    // rows {sr0 + 32i} (i=0..3), k-quad sq (4 fp32). Global loads: lin = i*256+t maps to
    // consecutive 128B segments -> fully coalesced.
    const int sq  = tid & 7;             // k-quad 0..7
    const int sr0 = tid >> 3;            // base row 0..31
    const float* Asrc = X + (size_t)(brow + sr0) * IN_K + sq * 4;
    const float* Bsrc = C + (size_t)(bcol + sr0) * IN_K + sq * 4;
    // LDS dest (bf16 elems): row r has 4 slots of 8 elems; phys slot = (sq>>1) ^ ((r>>1)&3)
    // -> ds_read_b128 fragments hit 8 distinct bank-groups (2-way = free), writes at floor.
    // (r>>1)&3 is invariant across i since rows step by 32.
    const int wofs = sr0 * 32 + (((sq >> 1) ^ ((sr0 >> 1) & 3)) * 8) + (sq & 1) * 4;

    float4 ar[4], br[4];
    float  xa[4] = {0.f, 0.f, 0.f, 0.f};
    float  ca[4] = {0.f, 0.f, 0.f, 0.f};

    auto load = [&](int kt) {
        #pragma unroll
        for (int i = 0; i < 4; ++i) {
            ar[i] = *reinterpret_cast<const float4*>(Asrc + (size_t)i * 32 * IN_K + kt * BK);
            br[i] = *reinterpret_cast<const float4*>(Bsrc + (size_t)i * 32 * IN_K + kt * BK);
        }
    };
    auto procstore = [&](int buf) {       // sumsq (fp32, pre-conversion) + cvt + LDS write
        #pragma unroll
        for (int i = 0; i < 4; ++i) {
            float4 a = ar[i], b = br[i];
            xa[i] += a.x*a.x + a.y*a.y + a.z*a.z + a.w*a.w;
            ca[i] += b.x*b.x + b.y*b.y + b.z*b.z + b.w*b.w;
            bf16x4 va = {(__bf16)a.x, (__bf16)a.y, (__bf16)a.z, (__bf16)a.w};
            bf16x4 vb = {(__bf16)b.x, (__bf16)b.y, (__bf16)b.z, (__bf16)b.w};
            *reinterpret_cast<bf16x4*>(&As[buf][wofs + i * 1024]) = va;
            *reinterpret_cast<bf16x4*>(&Bs[buf][wofs + i * 1024]) = vb;
        }
    };

    floatx4 acc[4][4];
    #pragma unroll
    for (int m = 0; m < 4; ++m)
        #pragma unroll
        for (int n = 0; n < 4; ++n)
            acc[m][n] = (floatx4){0.f, 0.f, 0.f, 0.f};

    load(0);
    procstore(0);

    #pragma unroll 1
    for (int kt = 0; kt < NKT; ++kt) {
        const int cur = kt & 1;
        __syncthreads();                      // buf[cur] ready for all waves
        if (kt < NKT - 1) load(kt + 1);       // issue next loads; latency hides under MFMA

        bf16x8 af[4], bfr[4];
        #pragma unroll
        for (int m = 0; m < 4; ++m) {
            int rr   = wr * 64 + m * 16 + l15;
            int phys = l4 ^ ((rr >> 1) & 3);
            af[m] = *reinterpret_cast<const bf16x8*>(&As[cur][rr * 32 + phys * 8]);
        }
        #pragma unroll
        for (int n = 0; n < 4; ++n) {
            int rr   = wc * 64 + n * 16 + l15;
            int phys = l4 ^ ((rr >> 1) & 3);
            bfr[n] = *reinterpret_cast<const bf16x8*>(&Bs[cur][rr * 32 + phys * 8]);
        }
        #pragma unroll
        for (int m = 0; m < 4; ++m)
            #pragma unroll
            for (int n = 0; n < 4; ++n)
                acc[m][n] = __builtin_amdgcn_mfma_f32_16x16x32_bf16(af[m], bfr[n], acc[m][n], 0, 0, 0);

        if (kt < NKT - 1) procstore(cur ^ 1); // convert+write next tile into other buffer
    }

    // Reduce per-thread sumsq partials (8 threads per row, consecutive lanes) -> LDS.
    #pragma unroll
    for (int i = 0; i < 4; ++i) {
        #pragma unroll
        for (int off = 1; off <= 4; off <<= 1) {
            xa[i] += __shfl_xor(xa[i], off, 64);
            ca[i] += __shfl_xor(ca[i], off, 64);
        }
    }
    if ((tid & 7) == 0) {
        #pragma unroll
        for (int i = 0; i < 4; ++i) {
            xsq_s[sr0 + 32 * i] = xa[i];
            csq_s[sr0 + 32 * i] = ca[i];
        }
    }
    __syncthreads();

    // Epilogue: d2 = max(xsq + csq - 2*cross, 0); out = exp(-d2 * exp(-2*ls))
    float xs[4][4];
    #pragma unroll
    for (int m = 0; m < 4; ++m) {
        int r0l = wr * 64 + m * 16 + l4 * 4;
        #pragma unroll
        for (int r = 0; r < 4; ++r) xs[m][r] = xsq_s[r0l + r];
    }

    #pragma unroll
    for (int n = 0; n < 4; ++n) {
        int cl    = wc * 64 + n * 16 + l15;
        float cs  = csq_s[cl];
        float inv = __expf(-2.f * LS[bcol + cl]);
        #pragma unroll
        for (int m = 0; m < 4; ++m) {
            int r0 = brow + wr * 64 + m * 16 + l4 * 4;
            #pragma unroll
            for (int r = 0; r < 4; ++r) {
                float d2 = fmaxf(xs[m][r] + cs - 2.f * acc[m][n][r], 0.f);
                out[(size_t)(r0 + r) * OUT_N + bcol + cl] = __expf(-d2 * inv);
            }
        }
    }
}

extern "C" void kernel_launch(void* const* d_in, const int* in_sizes, int n_in,
                              void* d_out, int out_size, void* d_ws, size_t ws_size,
                              hipStream_t stream) {
    const float* X  = (const float*)d_in[0];   // input   [8192][512]
    const float* C  = (const float*)d_in[1];   // centres [1024][512]
    const float* LS = (const float*)d_in[2];   // log_sigmas [1024]
    float* out = (float*)d_out;

    rbf_fused<<<(B_ROWS / 128) * (OUT_N / 128), 256, 0, stream>>>(X, C, LS, out);
}